// Round 14
// baseline (108.682 us; speedup 1.0000x reference)
//
#include <hip/hip_runtime.h>
#include <hip/hip_bf16.h>
#include <math.h>

typedef float f32x4 __attribute__((ext_vector_type(4)));
typedef __bf16 bf16_t;
typedef bf16_t bf16x8 __attribute__((ext_vector_type(8)));
typedef bf16_t bf16x4 __attribute__((ext_vector_type(4)));

__device__ __forceinline__ float act_softplus(float x) {
    return fmaxf(x, 0.f) + log1pf(expf(-fabsf(x)));
}
__device__ __forceinline__ float act_gelu(float x) {
    return 0.5f * x * (1.f + erff(x * 0.70710678118654752f));
}

// async global->LDS, 16B per lane; LDS dest = wave-uniform base + lane*16
__device__ __forceinline__ void gload_lds16(const bf16_t* g, bf16_t* l) {
    __builtin_amdgcn_global_load_lds(
        (const __attribute__((address_space(1))) unsigned int*)g,
        (__attribute__((address_space(3))) unsigned int*)l, 16, 0, 0);
}

template<int N_IMM>
__device__ __forceinline__ void wait_vmcnt() {
    if constexpr (N_IMM == 0) asm volatile("s_waitcnt vmcnt(0)" ::: "memory");
    else if constexpr (N_IMM == 2) asm volatile("s_waitcnt vmcnt(2)" ::: "memory");
    else if constexpr (N_IMM == 4) asm volatile("s_waitcnt vmcnt(4)" ::: "memory");
    else static_assert(N_IMM == 0, "unsupported vmcnt");
}

// ---------------- fused fp32 -> bf16 conversion for 3 arrays ----------------
__global__ __launch_bounds__(256) void cvt3(const float* __restrict__ a, bf16_t* __restrict__ ao, int na4,
                                            const float* __restrict__ b, bf16_t* __restrict__ bo, int nb4,
                                            const float* __restrict__ c, bf16_t* __restrict__ co, int nc4) {
    int q = blockIdx.x * 256 + threadIdx.x;   // quad index
    const float* src; bf16_t* dst;
    if (q < na4)            { src = a + (size_t)q * 4;              dst = ao + (size_t)q * 4; }
    else if (q < na4 + nb4) { int r = q - na4; src = b + (size_t)r * 4; dst = bo + (size_t)r * 4; }
    else if (q < na4 + nb4 + nc4) { int r = q - na4 - nb4; src = c + (size_t)r * 4; dst = co + (size_t)r * 4; }
    else return;
    float4 v = *reinterpret_cast<const float4*>(src);
    bf16x4 o;
    o[0] = (bf16_t)v.x; o[1] = (bf16_t)v.y; o[2] = (bf16_t)v.z; o[3] = (bf16_t)v.w;
    *reinterpret_cast<bf16x4*>(dst) = o;
}

// ---------------- merged qkvg GEMM: section-dedicated XCD mapping + NT stores ----------------
// R13 champion body (static 2-buffer, depth-1 counted vmcnt(2), raw barriers,
// source-preswizzled linear LDS, 16KB LDS -> 8 blocks/CU, activated fp32 out).
// NEW (R14): (1) XCD pair {2s,2s+1} owns section s (m-halves) -> per-XCD
// working set = 2MB A-half + 2MB W-section = exactly 4MB L2 (was 5MB mixed).
// (2) __builtin_nontemporal_store for the 40MB output stream so it does not
// evict the operand set from L2 (consumers re-read via L3).
__global__ __launch_bounds__(256) void gemm_qkvg(const bf16_t* __restrict__ A,
                                                 const bf16_t* __restrict__ Wall,
                                                 const float* __restrict__ biasAll,
                                                 float* __restrict__ OutAll) {
    constexpr int BM = 64, BN = 64, MR = 2, NR = 2;
    constexpr int K = 1024, M = 2048, N = 1024;
    constexpr int TNUM = K / 32;                // 32, even
    constexpr int LOADS = 2;

    __shared__ __align__(16) bf16_t Sa0[BM * 32];
    __shared__ __align__(16) bf16_t Sb0[BN * 32];
    __shared__ __align__(16) bf16_t Sa1[BM * 32];
    __shared__ __align__(16) bf16_t Sb1[BN * 32];

    // section-dedicated XCD mapping (blockIdx%8 == XCD assumption, R4-verified):
    // xcd = 2*sec + mhalf; per XCD: 16 m-tiles x 16 n-tiles of one section.
    const int xcd = blockIdx.x & 7;
    const int idx = blockIdx.x >> 3;            // 0..255
    const int sec = xcd >> 1;                   // 0..3 (q,k,v,g)
    const int mhalf = xcd & 1;
    const int mt = mhalf * 16 + (idx & 15);     // 0..31
    const int nt = idx >> 4;                    // 0..15
    const int m0 = mt * BM, n0 = nt * BN;

    const bf16_t* B = Wall + (size_t)sec * 1024 * 1024;
    const float* bias = biasAll + sec * 1024;
    float* Cout = OutAll + (size_t)sec * 2048 * 1024;

    const int tid = threadIdx.x;
    const int lane = tid & 63;
    const int w = tid >> 6;
    const int wr = w >> 1, wc = w & 1;          // 2x2 waves of 32x32

    const int l15 = lane & 15, lg = lane >> 4;
    const int srow = lane >> 2, pos = lane & 3;

    f32x4 acc[MR][NR] = {};

    auto stageTo = [&](bf16_t* Ad, bf16_t* Bd, int k0) {
        int row = w * 16 + srow;
        int ch = pos ^ ((row >> 1) & 3);
        gload_lds16(&A[(size_t)(m0 + row) * K + k0 + ch * 8], &Ad[w * 512]);
        gload_lds16(&B[(size_t)(n0 + row) * K + k0 + ch * 8], &Bd[w * 512]);
    };

    auto compute = [&](const bf16_t* Ac, const bf16_t* Bc) {
        bf16x8 af[MR], bfr[NR];
#pragma unroll
        for (int i = 0; i < MR; ++i) {
            int ar = wr * MR * 16 + i * 16 + l15;
            af[i] = *(const bf16x8*)(&Ac[ar * 32 + (lg ^ ((ar >> 1) & 3)) * 8]);
        }
#pragma unroll
        for (int j = 0; j < NR; ++j) {
            int br = wc * NR * 16 + j * 16 + l15;
            bfr[j] = *(const bf16x8*)(&Bc[br * 32 + (lg ^ ((br >> 1) & 3)) * 8]);
        }
#pragma unroll
        for (int i = 0; i < MR; ++i)
#pragma unroll
            for (int j = 0; j < NR; ++j)
                acc[i][j] = __builtin_amdgcn_mfma_f32_16x16x32_bf16(af[i], bfr[j], acc[i][j], 0, 0, 0);
    };

    stageTo(Sa0, Sb0, 0);
    for (int t = 0; t < TNUM; t += 2) {
        // phase A: tile t in S0
        if (t + 1 < TNUM) { stageTo(Sa1, Sb1, (t + 1) * 32); wait_vmcnt<LOADS>(); }
        else              { wait_vmcnt<0>(); }
        __builtin_amdgcn_s_barrier();
        __builtin_amdgcn_sched_barrier(0);
        compute(Sa0, Sb0);
        __builtin_amdgcn_sched_barrier(0);
        __builtin_amdgcn_s_barrier();

        // phase B: tile t+1 in S1
        if (t + 2 < TNUM) { stageTo(Sa0, Sb0, (t + 2) * 32); wait_vmcnt<LOADS>(); }
        else              { wait_vmcnt<0>(); }
        __builtin_amdgcn_s_barrier();
        __builtin_amdgcn_sched_barrier(0);
        compute(Sa1, Sb1);
        __builtin_amdgcn_sched_barrier(0);
        __builtin_amdgcn_s_barrier();
    }

    // epilogue: bias + activation (high TLP), NON-TEMPORAL fp32 dense stores
#pragma unroll
    for (int i = 0; i < MR; ++i) {
        int gm_base = m0 + wr * MR * 16 + i * 16 + lg * 4;
#pragma unroll
        for (int j = 0; j < NR; ++j) {
            int gn = n0 + wc * NR * 16 + j * 16 + l15;
            float bv = bias[gn];
#pragma unroll
            for (int r = 0; r < 4; ++r) {
                int gm = gm_base + r;
                float v = acc[i][j][r] + bv;
                float a = (sec < 2) ? act_softplus(v) : act_gelu(v);
                __builtin_nontemporal_store(a, &Cout[(size_t)gm * N + gn]);
            }
        }
    }
}

// ---------------- GEMM2: R9 proven fp32-dense template (NT stores added) ----------------
template<int BM, int BN, int MR, int NR>
__global__ __launch_bounds__(256) void gemm_bt(const bf16_t* __restrict__ A,
                                               const bf16_t* __restrict__ B,
                                               const float* __restrict__ bias,
                                               float* __restrict__ Cout,
                                               int M, int N) {
    constexpr int K = 1024;
    constexpr int TNUM = K / 32;
    constexpr int WCOLS = BN / (NR * 16);
    constexpr int WROWS = BM / (MR * 16);
    static_assert(WROWS * WCOLS == 4, "4 waves");
    constexpr int ASEG = BM / 64, BSEG = BN / 64;
    constexpr int LOADS = ASEG + BSEG;

    __shared__ __align__(16) bf16_t Sa0[BM * 32];
    __shared__ __align__(16) bf16_t Sb0[BN * 32];
    __shared__ __align__(16) bf16_t Sa1[BM * 32];
    __shared__ __align__(16) bf16_t Sb1[BN * 32];
    __shared__ __align__(16) bf16_t Sa2[BM * 32];
    __shared__ __align__(16) bf16_t Sb2[BN * 32];

    const int tid = threadIdx.x;
    const int lane = tid & 63;
    const int w = tid >> 6;
    const int wr = w / WCOLS, wc = w % WCOLS;

    const int NTM = M / BM, NTN = N / BN;
    const int CHM = NTM >> 3;
    const int chunkN = (NTN * CHM) >> 3;
    const int c = blockIdx.x & 7;
    const int pp = blockIdx.x >> 3;
    const int mt = (c % CHM) * 8 + (pp & 7);
    const int nt = (c / CHM) * chunkN + (pp >> 3);
    const int m0 = mt * BM, n0 = nt * BN;

    const int l15 = lane & 15, lg = lane >> 4;
    const int srow = lane >> 2, pos = lane & 3;

    f32x4 acc[MR][NR] = {};

    auto stageTo = [&](bf16_t* Ad, bf16_t* Bd, int k0) {
#pragma unroll
        for (int t = 0; t < ASEG; ++t) {
            int s = w + t * 4;
            int row = s * 16 + srow;
            int ch = pos ^ ((row >> 1) & 3);
            gload_lds16(&A[(size_t)(m0 + row) * K + k0 + ch * 8], &Ad[s * 512]);
        }
#pragma unroll
        for (int t = 0; t < BSEG; ++t) {
            int s = w + t * 4;
            int row = s * 16 + srow;
            int ch = pos ^ ((row >> 1) & 3);
            gload_lds16(&B[(size_t)(n0 + row) * K + k0 + ch * 8], &Bd[s * 512]);
        }
    };

    auto compute = [&](const bf16_t* Ac, const bf16_t* Bc) {
        bf16x8 af[MR], bfr[NR];
#pragma unroll
        for (int i = 0; i < MR; ++i) {
            int ar = wr * MR * 16 + i * 16 + l15;
            af[i] = *(const bf16x8*)(&Ac[ar * 32 + (lg ^ ((ar >> 1) & 3)) * 8]);
        }
#pragma unroll
        for (int j = 0; j < NR; ++j) {
            int br = wc * NR * 16 + j * 16 + l15;
            bfr[j] = *(const bf16x8*)(&Bc[br * 32 + (lg ^ ((br >> 1) & 3)) * 8]);
        }
#pragma unroll
        for (int i = 0; i < MR; ++i)
#pragma unroll
            for (int j = 0; j < NR; ++j)
                acc[i][j] = __builtin_amdgcn_mfma_f32_16x16x32_bf16(af[i], bfr[j], acc[i][j], 0, 0, 0);
    };

    stageTo(Sa0, Sb0, 0);
    stageTo(Sa1, Sb1, 32);

    for (int t = 0; t < TNUM - 2; t += 3) {
        wait_vmcnt<LOADS>();
        __builtin_amdgcn_s_barrier();
        __builtin_amdgcn_sched_barrier(0);
        stageTo(Sa2, Sb2, (t + 2) * 32);
        compute(Sa0, Sb0);
        __builtin_amdgcn_sched_barrier(0);

        wait_vmcnt<LOADS>();
        __builtin_amdgcn_s_barrier();
        __builtin_amdgcn_sched_barrier(0);
        stageTo(Sa0, Sb0, (t + 3) * 32);
        compute(Sa1, Sb1);
        __builtin_amdgcn_sched_barrier(0);

        wait_vmcnt<LOADS>();
        __builtin_amdgcn_s_barrier();
        __builtin_amdgcn_sched_barrier(0);
        stageTo(Sa1, Sb1, (t + 4) * 32);
        compute(Sa2, Sb2);
        __builtin_amdgcn_sched_barrier(0);
    }
    wait_vmcnt<LOADS>();
    __builtin_amdgcn_s_barrier();
    __builtin_amdgcn_sched_barrier(0);
    compute(Sa0, Sb0);
    __builtin_amdgcn_sched_barrier(0);

    wait_vmcnt<0>();
    __builtin_amdgcn_s_barrier();
    __builtin_amdgcn_sched_barrier(0);
    compute(Sa1, Sb1);

#pragma unroll
    for (int i = 0; i < MR; ++i) {
        int gm_base = m0 + wr * MR * 16 + i * 16 + lg * 4;
#pragma unroll
        for (int j = 0; j < NR; ++j) {
            int gn = n0 + wc * NR * 16 + j * 16 + l15;
            float bv = bias[gn];
#pragma unroll
            for (int r = 0; r < 4; ++r) {
                int gm = gm_base + r;
                __builtin_nontemporal_store(acc[i][j][r] + bv, &Cout[(size_t)gm * N + gn]);
            }
        }
    }
}

// ---------------- A = K^T Q partials per (b,h); q,k PRE-ACTIVATED fp32 dense ----------------
__global__ __launch_bounds__(256) void attn_A(const float* __restrict__ qkvgf,
                                              float* __restrict__ Apart) {
    const int bh = blockIdx.x;           // 0..31
    const int p = blockIdx.y;            // 0..7
    const int b = bh >> 4, h = bh & 15;
    const int tid = threadIdx.x;
    __shared__ float ks[32][64];
    __shared__ float qs[32][64];
    float acc[4][4] = {};
    const int dg = tid >> 4, eg = tid & 15;
    const int stok = tid >> 3, se0 = (tid & 7) * 8;
    const float* qf = qkvgf;                              // section 0
    const float* kf = qkvgf + (size_t)2048 * 1024;        // section 1

    for (int t0 = p * 128; t0 < p * 128 + 128; t0 += 32) {
        __syncthreads();
        size_t rowb = (size_t)(b * 1024 + t0 + stok) * 1024 + h * 64 + se0;
        float4 q0 = *(const float4*)(&qf[rowb]);
        float4 q1 = *(const float4*)(&qf[rowb + 4]);
        float4 k0 = *(const float4*)(&kf[rowb]);
        float4 k1 = *(const float4*)(&kf[rowb + 4]);
        *(float4*)(&qs[stok][se0]) = q0;
        *(float4*)(&qs[stok][se0 + 4]) = q1;
        *(float4*)(&ks[stok][se0]) = k0;
        *(float4*)(&ks[stok][se0 + 4]) = k1;
        __syncthreads();
#pragma unroll 8
        for (int tt = 0; tt < 32; ++tt) {
            f32x4 kv = *(const f32x4*)(&ks[tt][dg * 4]);
            f32x4 qv = *(const f32x4*)(&qs[tt][eg * 4]);
#pragma unroll
            for (int i = 0; i < 4; ++i)
#pragma unroll
                for (int j = 0; j < 4; ++j) acc[i][j] += kv[i] * qv[j];
        }
    }
    float* dst = Apart + ((size_t)p * 32 + bh) * 4096;
#pragma unroll
    for (int i = 0; i < 4; ++i)
#pragma unroll
        for (int j = 0; j < 4; ++j)
            dst[(dg * 4 + i) * 64 + eg * 4 + j] = acc[i][j];
}

// ---------------- reduce partials -> A, compute z ----------------
__global__ __launch_bounds__(256) void reduce_A_z(const float* __restrict__ Apart,
                                                  float* __restrict__ A,
                                                  float* __restrict__ z) {
    const int bh = blockIdx.x;
    const int tid = threadIdx.x;
    __shared__ float As[4096];
    for (int i0 = tid * 4; i0 < 4096; i0 += 1024) {
        f32x4 s = {};
#pragma unroll
        for (int p = 0; p < 8; ++p) {
            f32x4 v = *(const f32x4*)(&Apart[((size_t)p * 32 + bh) * 4096 + i0]);
            s += v;
        }
        *(f32x4*)(&As[i0]) = s;
        *(f32x4*)(&A[(size_t)bh * 4096 + i0]) = s;
    }
    __syncthreads();
    if (tid < 64) {
        float s = 0.f;
#pragma unroll 8
        for (int d = 0; d < 64; ++d) s += As[d * 64 + tid];
        z[bh * 64 + tid] = 1.0f / (s * 0.125f + 1024.0f);
    }
}

// ---------------- Y = ((SCALE*V@A + V) * z * g); v,g PRE-ACTIVATED fp32 dense ----------------
__global__ __launch_bounds__(256) void out_Y(const float* __restrict__ qkvgf,
                                             const float* __restrict__ A,
                                             const float* __restrict__ z,
                                             bf16_t* __restrict__ Y) {
    const int bh = blockIdx.x;
    const int b = bh >> 4, h = bh & 15;
    const int chunk = blockIdx.y;        // 0..15 -> 64 tokens
    const int tid = threadIdx.x;
    __shared__ float As[64][64];         // A[d][e]
    __shared__ float vs[32][64];
    __shared__ float zs[64];
    for (int i = tid; i < 4096; i += 256) As[i >> 6][i & 63] = A[(size_t)bh * 4096 + i];
    if (tid < 64) zs[tid] = z[bh * 64 + tid];
    const float* vf = qkvgf + (size_t)2 * 2048 * 1024;    // section 2
    const float* gf = qkvgf + (size_t)3 * 2048 * 1024;    // section 3
    const int e = tid & 63, trow = tid >> 6;
    const int stok = tid >> 3, se0 = (tid & 7) * 8;

    for (int t0 = chunk * 64; t0 < chunk * 64 + 64; t0 += 32) {
        __syncthreads();
        size_t rowb = (size_t)(b * 1024 + t0 + stok) * 1024 + h * 64 + se0;
        float4 v0 = *(const float4*)(&vf[rowb]);
        float4 v1 = *(const float4*)(&vf[rowb + 4]);
        *(float4*)(&vs[stok][se0]) = v0;
        *(float4*)(&vs[stok][se0 + 4]) = v1;
        __syncthreads();
#pragma unroll
        for (int kk = 0; kk < 8; ++kk) {
            int ml = trow * 8 + kk;
            int m = t0 + ml;
            float s = 0.f;
#pragma unroll 8
            for (int d = 0; d < 64; ++d) s += vs[ml][d] * As[d][e];
            float g = gf[(size_t)(b * 1024 + m) * 1024 + h * 64 + e];
            float o = (s * 0.125f + vs[ml][e]) * zs[e] * g;
            Y[((size_t)b * 1024 + h * 64 + (m >> 4)) * 1024 + ((m & 15) << 6) + e] = (bf16_t)o;
        }
    }
}

extern "C" void kernel_launch(void* const* d_in, const int* in_sizes, int n_in,
                              void* d_out, int out_size, void* d_ws, size_t ws_size,
                              hipStream_t stream) {
    const float* x      = (const float*)d_in[0];
    const float* w_qkvg = (const float*)d_in[1];
    const float* b_qkvg = (const float*)d_in[2];
    const float* w_proj = (const float*)d_in[3];
    const float* b_proj = (const float*)d_in[4];

    char* p = (char*)d_ws;
    bf16_t* xb    = (bf16_t*)p; p += (size_t)2048 * 1024 * 2;       // 4MB
    bf16_t* w1b   = (bf16_t*)p; p += (size_t)4096 * 1024 * 2;       // 8MB
    bf16_t* w2b   = (bf16_t*)p; p += (size_t)1024 * 1024 * 2;       // 2MB
    float*  qkvgf = (float*)p;  p += (size_t)4 * 2048 * 1024 * 4;   // 32MB activated fp32, 4 dense sections
    float*  Apart = (float*)p;  p += (size_t)8 * 32 * 4096 * 4;     // 4MB
    float*  Afull = (float*)p;  p += (size_t)32 * 4096 * 4;
    float*  zbuf  = (float*)p;  p += (size_t)32 * 64 * 4;
    bf16_t* Ybuf  = (bf16_t*)p; p += (size_t)2048 * 1024 * 2;       // 4MB

    // quad counts: x 524288, w_qkvg 1048576, w_proj 262144 -> 7168 blocks
    cvt3<<<7168, 256, 0, stream>>>(x, xb, 524288, w_qkvg, w1b, 1048576, w_proj, w2b, 262144);

    // merged qkvg GEMM: 2048 blocks, section-dedicated XCDs, activated fp32 NT out
    gemm_qkvg<<<2048, 256, 0, stream>>>(xb, w1b, b_qkvg, qkvgf);

    attn_A<<<dim3(32, 8), 256, 0, stream>>>(qkvgf, Apart);
    reduce_A_z<<<32, 256, 0, stream>>>(Apart, Afull, zbuf);
    out_Y<<<dim3(32, 16), 256, 0, stream>>>(qkvgf, Afull, zbuf, Ybuf);
    // GEMM2: fp32 dense NT out
    gemm_bt<64, 64, 2, 2><<<512, 256, 0, stream>>>(Ybuf, w2b, b_proj, (float*)d_out, 2048, 1024);
}

// Round 15
// 103.934 us; speedup vs baseline: 1.0457x; 1.0457x over previous
//
#include <hip/hip_runtime.h>
#include <hip/hip_bf16.h>
#include <math.h>

typedef float f32x4 __attribute__((ext_vector_type(4)));
typedef __bf16 bf16_t;
typedef bf16_t bf16x8 __attribute__((ext_vector_type(8)));
typedef bf16_t bf16x4 __attribute__((ext_vector_type(4)));

__device__ __forceinline__ float act_softplus(float x) {
    return fmaxf(x, 0.f) + log1pf(expf(-fabsf(x)));
}
__device__ __forceinline__ float act_gelu(float x) {
    return 0.5f * x * (1.f + erff(x * 0.70710678118654752f));
}

// async global->LDS, 16B per lane; LDS dest = wave-uniform base + lane*16
__device__ __forceinline__ void gload_lds16(const bf16_t* g, bf16_t* l) {
    __builtin_amdgcn_global_load_lds(
        (const __attribute__((address_space(1))) unsigned int*)g,
        (__attribute__((address_space(3))) unsigned int*)l, 16, 0, 0);
}

template<int N_IMM>
__device__ __forceinline__ void wait_vmcnt() {
    if constexpr (N_IMM == 0) asm volatile("s_waitcnt vmcnt(0)" ::: "memory");
    else if constexpr (N_IMM == 2) asm volatile("s_waitcnt vmcnt(2)" ::: "memory");
    else if constexpr (N_IMM == 4) asm volatile("s_waitcnt vmcnt(4)" ::: "memory");
    else static_assert(N_IMM == 0, "unsupported vmcnt");
}

// ---------------- fused fp32 -> bf16 conversion for 3 arrays ----------------
__global__ __launch_bounds__(256) void cvt3(const float* __restrict__ a, bf16_t* __restrict__ ao, int na4,
                                            const float* __restrict__ b, bf16_t* __restrict__ bo, int nb4,
                                            const float* __restrict__ c, bf16_t* __restrict__ co, int nc4) {
    int q = blockIdx.x * 256 + threadIdx.x;   // quad index
    const float* src; bf16_t* dst;
    if (q < na4)            { src = a + (size_t)q * 4;              dst = ao + (size_t)q * 4; }
    else if (q < na4 + nb4) { int r = q - na4; src = b + (size_t)r * 4; dst = bo + (size_t)r * 4; }
    else if (q < na4 + nb4 + nc4) { int r = q - na4 - nb4; src = c + (size_t)r * 4; dst = co + (size_t)r * 4; }
    else return;
    float4 v = *reinterpret_cast<const float4*>(src);
    bf16x4 o;
    o[0] = (bf16_t)v.x; o[1] = (bf16_t)v.y; o[2] = (bf16_t)v.z; o[3] = (bf16_t)v.w;
    *reinterpret_cast<bf16x4*>(dst) = o;
}

// ---------------- merged qkvg GEMM: 128x128 tile, 8 waves, 2x staging reuse ----------------
// R15: same champion pipeline (static 2-buffer, depth-1 counted vmcnt(2), raw
// barriers, source-preswizzled linear LDS), but 128x128 tile at 512 threads:
// staged bytes per MFMA halves (512B -> 256B) while keeping 16 waves/CU
// (grid 512 = 2 blocks/CU, 32KB LDS). Tests the staging-BW model
// (~16-22B/cy/CU on the global_load_lds path) that unifies R2-R14.
// Section-dedicated XCD chunks: chunk c -> section c/2, 2MB A + 2MB W per XCD.
// Epilogue: bias + activation at high TLP, plain fp32 dense stores (R13-fast).
__global__ __launch_bounds__(512) void gemm_qkvg(const bf16_t* __restrict__ A,
                                                 const bf16_t* __restrict__ Wall,
                                                 const float* __restrict__ biasAll,
                                                 float* __restrict__ OutAll) {
    constexpr int BM = 128, BN = 128, MR = 4, NR = 2;
    constexpr int K = 1024, M = 2048;
    constexpr int TNUM = K / 32;                // 32, even
    constexpr int LOADS = 2;

    __shared__ __align__(16) bf16_t Sa0[BM * 32];
    __shared__ __align__(16) bf16_t Sb0[BN * 32];
    __shared__ __align__(16) bf16_t Sa1[BM * 32];
    __shared__ __align__(16) bf16_t Sb1[BN * 32];

    const int tid = threadIdx.x;
    const int lane = tid & 63;
    const int w = tid >> 6;                     // 0..7
    const int wr = w >> 2, wc = w & 3;          // 2x4 waves; per-wave 64x32

    // XCD chunk swizzle: 8 chunks of 8 m-tiles x 8 n-tiles (2MB A + 2MB W each).
    // chunk c: cm=c&1 (m half), cn=c>>1 (0..3) == section (n-tiles 8*cn..8*cn+7).
    const int c = blockIdx.x & 7;
    const int pp = blockIdx.x >> 3;             // 0..63
    const int mt = (c & 1) * 8 + (pp & 7);      // 0..15
    const int ntG = (c >> 1) * 8 + (pp >> 3);   // 0..31 global n-tile
    const int m0 = mt * BM;
    const int sec = ntG >> 3;                   // 0..3 (q,k,v,g)
    const int n0 = (ntG & 7) * BN;              // col base within section

    const bf16_t* B = Wall + (size_t)sec * 1024 * 1024;
    const float* bias = biasAll + sec * 1024;
    float* Cout = OutAll + (size_t)sec * 2048 * 1024;

    const int l15 = lane & 15, lg = lane >> 4;
    const int srow = lane >> 2, pos = lane & 3;

    f32x4 acc[MR][NR] = {};

    // stage: 512 threads x 16B = 8KB = full 128x32 tile per call (1 A + 1 B)
    auto stageTo = [&](bf16_t* Ad, bf16_t* Bd, int k0) {
        int row = w * 16 + srow;                // 0..127
        int ch = pos ^ ((row >> 1) & 3);
        gload_lds16(&A[(size_t)(m0 + row) * K + k0 + ch * 8], &Ad[w * 512]);
        gload_lds16(&B[(size_t)(n0 + row) * K + k0 + ch * 8], &Bd[w * 512]);
    };

    auto compute = [&](const bf16_t* Ac, const bf16_t* Bc) {
        bf16x8 af[MR], bfr[NR];
#pragma unroll
        for (int i = 0; i < MR; ++i) {
            int ar = wr * 64 + i * 16 + l15;
            af[i] = *(const bf16x8*)(&Ac[ar * 32 + (lg ^ ((ar >> 1) & 3)) * 8]);
        }
#pragma unroll
        for (int j = 0; j < NR; ++j) {
            int br = wc * 32 + j * 16 + l15;
            bfr[j] = *(const bf16x8*)(&Bc[br * 32 + (lg ^ ((br >> 1) & 3)) * 8]);
        }
#pragma unroll
        for (int i = 0; i < MR; ++i)
#pragma unroll
            for (int j = 0; j < NR; ++j)
                acc[i][j] = __builtin_amdgcn_mfma_f32_16x16x32_bf16(af[i], bfr[j], acc[i][j], 0, 0, 0);
    };

    stageTo(Sa0, Sb0, 0);
    for (int t = 0; t < TNUM; t += 2) {
        // phase A: tile t in S0
        if (t + 1 < TNUM) { stageTo(Sa1, Sb1, (t + 1) * 32); wait_vmcnt<LOADS>(); }
        else              { wait_vmcnt<0>(); }
        __builtin_amdgcn_s_barrier();
        __builtin_amdgcn_sched_barrier(0);
        compute(Sa0, Sb0);
        __builtin_amdgcn_sched_barrier(0);
        __builtin_amdgcn_s_barrier();

        // phase B: tile t+1 in S1
        if (t + 2 < TNUM) { stageTo(Sa0, Sb0, (t + 2) * 32); wait_vmcnt<LOADS>(); }
        else              { wait_vmcnt<0>(); }
        __builtin_amdgcn_s_barrier();
        __builtin_amdgcn_sched_barrier(0);
        compute(Sa1, Sb1);
        __builtin_amdgcn_sched_barrier(0);
        __builtin_amdgcn_s_barrier();
    }

    // epilogue: bias + activation (high TLP), plain fp32 dense stores
#pragma unroll
    for (int i = 0; i < MR; ++i) {
        int gm_base = m0 + wr * 64 + i * 16 + lg * 4;
#pragma unroll
        for (int j = 0; j < NR; ++j) {
            int gn = n0 + wc * 32 + j * 16 + l15;
            float bv = bias[gn];
#pragma unroll
            for (int r = 0; r < 4; ++r) {
                int gm = gm_base + r;
                float v = acc[i][j][r] + bv;
                float a = (sec < 2) ? act_softplus(v) : act_gelu(v);
                Cout[(size_t)gm * 1024 + gn] = a;
            }
        }
    }
}

// ---------------- GEMM2: R9 proven fp32-dense template (unchanged) ----------------
template<int BM, int BN, int MR, int NR>
__global__ __launch_bounds__(256) void gemm_bt(const bf16_t* __restrict__ A,
                                               const bf16_t* __restrict__ B,
                                               const float* __restrict__ bias,
                                               float* __restrict__ Cout,
                                               int M, int N) {
    constexpr int K = 1024;
    constexpr int TNUM = K / 32;
    constexpr int WCOLS = BN / (NR * 16);
    constexpr int WROWS = BM / (MR * 16);
    static_assert(WROWS * WCOLS == 4, "4 waves");
    constexpr int ASEG = BM / 64, BSEG = BN / 64;
    constexpr int LOADS = ASEG + BSEG;

    __shared__ __align__(16) bf16_t Sa0[BM * 32];
    __shared__ __align__(16) bf16_t Sb0[BN * 32];
    __shared__ __align__(16) bf16_t Sa1[BM * 32];
    __shared__ __align__(16) bf16_t Sb1[BN * 32];
    __shared__ __align__(16) bf16_t Sa2[BM * 32];
    __shared__ __align__(16) bf16_t Sb2[BN * 32];

    const int tid = threadIdx.x;
    const int lane = tid & 63;
    const int w = tid >> 6;
    const int wr = w / WCOLS, wc = w % WCOLS;

    const int NTM = M / BM, NTN = N / BN;
    const int CHM = NTM >> 3;
    const int chunkN = (NTN * CHM) >> 3;
    const int c = blockIdx.x & 7;
    const int pp = blockIdx.x >> 3;
    const int mt = (c % CHM) * 8 + (pp & 7);
    const int nt = (c / CHM) * chunkN + (pp >> 3);
    const int m0 = mt * BM, n0 = nt * BN;

    const int l15 = lane & 15, lg = lane >> 4;
    const int srow = lane >> 2, pos = lane & 3;

    f32x4 acc[MR][NR] = {};

    auto stageTo = [&](bf16_t* Ad, bf16_t* Bd, int k0) {
#pragma unroll
        for (int t = 0; t < ASEG; ++t) {
            int s = w + t * 4;
            int row = s * 16 + srow;
            int ch = pos ^ ((row >> 1) & 3);
            gload_lds16(&A[(size_t)(m0 + row) * K + k0 + ch * 8], &Ad[s * 512]);
        }
#pragma unroll
        for (int t = 0; t < BSEG; ++t) {
            int s = w + t * 4;
            int row = s * 16 + srow;
            int ch = pos ^ ((row >> 1) & 3);
            gload_lds16(&B[(size_t)(n0 + row) * K + k0 + ch * 8], &Bd[s * 512]);
        }
    };

    auto compute = [&](const bf16_t* Ac, const bf16_t* Bc) {
        bf16x8 af[MR], bfr[NR];
#pragma unroll
        for (int i = 0; i < MR; ++i) {
            int ar = wr * MR * 16 + i * 16 + l15;
            af[i] = *(const bf16x8*)(&Ac[ar * 32 + (lg ^ ((ar >> 1) & 3)) * 8]);
        }
#pragma unroll
        for (int j = 0; j < NR; ++j) {
            int br = wc * NR * 16 + j * 16 + l15;
            bfr[j] = *(const bf16x8*)(&Bc[br * 32 + (lg ^ ((br >> 1) & 3)) * 8]);
        }
#pragma unroll
        for (int i = 0; i < MR; ++i)
#pragma unroll
            for (int j = 0; j < NR; ++j)
                acc[i][j] = __builtin_amdgcn_mfma_f32_16x16x32_bf16(af[i], bfr[j], acc[i][j], 0, 0, 0);
    };

    stageTo(Sa0, Sb0, 0);
    stageTo(Sa1, Sb1, 32);

    for (int t = 0; t < TNUM - 2; t += 3) {
        wait_vmcnt<LOADS>();
        __builtin_amdgcn_s_barrier();
        __builtin_amdgcn_sched_barrier(0);
        stageTo(Sa2, Sb2, (t + 2) * 32);
        compute(Sa0, Sb0);
        __builtin_amdgcn_sched_barrier(0);

        wait_vmcnt<LOADS>();
        __builtin_amdgcn_s_barrier();
        __builtin_amdgcn_sched_barrier(0);
        stageTo(Sa0, Sb0, (t + 3) * 32);
        compute(Sa1, Sb1);
        __builtin_amdgcn_sched_barrier(0);

        wait_vmcnt<LOADS>();
        __builtin_amdgcn_s_barrier();
        __builtin_amdgcn_sched_barrier(0);
        stageTo(Sa1, Sb1, (t + 4) * 32);
        compute(Sa2, Sb2);
        __builtin_amdgcn_sched_barrier(0);
    }
    wait_vmcnt<LOADS>();
    __builtin_amdgcn_s_barrier();
    __builtin_amdgcn_sched_barrier(0);
    compute(Sa0, Sb0);
    __builtin_amdgcn_sched_barrier(0);

    wait_vmcnt<0>();
    __builtin_amdgcn_s_barrier();
    __builtin_amdgcn_sched_barrier(0);
    compute(Sa1, Sb1);

#pragma unroll
    for (int i = 0; i < MR; ++i) {
        int gm_base = m0 + wr * MR * 16 + i * 16 + lg * 4;
#pragma unroll
        for (int j = 0; j < NR; ++j) {
            int gn = n0 + wc * NR * 16 + j * 16 + l15;
            float bv = bias[gn];
#pragma unroll
            for (int r = 0; r < 4; ++r) {
                int gm = gm_base + r;
                Cout[(size_t)gm * N + gn] = acc[i][j][r] + bv;
            }
        }
    }
}

// ---------------- A = K^T Q partials per (b,h); q,k PRE-ACTIVATED fp32 dense ----------------
__global__ __launch_bounds__(256) void attn_A(const float* __restrict__ qkvgf,
                                              float* __restrict__ Apart) {
    const int bh = blockIdx.x;           // 0..31
    const int p = blockIdx.y;            // 0..7
    const int b = bh >> 4, h = bh & 15;
    const int tid = threadIdx.x;
    __shared__ float ks[32][64];
    __shared__ float qs[32][64];
    float acc[4][4] = {};
    const int dg = tid >> 4, eg = tid & 15;
    const int stok = tid >> 3, se0 = (tid & 7) * 8;
    const float* qf = qkvgf;                              // section 0
    const float* kf = qkvgf + (size_t)2048 * 1024;        // section 1

    for (int t0 = p * 128; t0 < p * 128 + 128; t0 += 32) {
        __syncthreads();
        size_t rowb = (size_t)(b * 1024 + t0 + stok) * 1024 + h * 64 + se0;
        float4 q0 = *(const float4*)(&qf[rowb]);
        float4 q1 = *(const float4*)(&qf[rowb + 4]);
        float4 k0 = *(const float4*)(&kf[rowb]);
        float4 k1 = *(const float4*)(&kf[rowb + 4]);
        *(float4*)(&qs[stok][se0]) = q0;
        *(float4*)(&qs[stok][se0 + 4]) = q1;
        *(float4*)(&ks[stok][se0]) = k0;
        *(float4*)(&ks[stok][se0 + 4]) = k1;
        __syncthreads();
#pragma unroll 8
        for (int tt = 0; tt < 32; ++tt) {
            f32x4 kv = *(const f32x4*)(&ks[tt][dg * 4]);
            f32x4 qv = *(const f32x4*)(&qs[tt][eg * 4]);
#pragma unroll
            for (int i = 0; i < 4; ++i)
#pragma unroll
                for (int j = 0; j < 4; ++j) acc[i][j] += kv[i] * qv[j];
        }
    }
    float* dst = Apart + ((size_t)p * 32 + bh) * 4096;
#pragma unroll
    for (int i = 0; i < 4; ++i)
#pragma unroll
        for (int j = 0; j < 4; ++j)
            dst[(dg * 4 + i) * 64 + eg * 4 + j] = acc[i][j];
}

// ---------------- reduce partials -> A, compute z ----------------
__global__ __launch_bounds__(256) void reduce_A_z(const float* __restrict__ Apart,
                                                  float* __restrict__ A,
                                                  float* __restrict__ z) {
    const int bh = blockIdx.x;
    const int tid = threadIdx.x;
    __shared__ float As[4096];
    for (int i0 = tid * 4; i0 < 4096; i0 += 1024) {
        f32x4 s = {};
#pragma unroll
        for (int p = 0; p < 8; ++p) {
            f32x4 v = *(const f32x4*)(&Apart[((size_t)p * 32 + bh) * 4096 + i0]);
            s += v;
        }
        *(f32x4*)(&As[i0]) = s;
        *(f32x4*)(&A[(size_t)bh * 4096 + i0]) = s;
    }
    __syncthreads();
    if (tid < 64) {
        float s = 0.f;
#pragma unroll 8
        for (int d = 0; d < 64; ++d) s += As[d * 64 + tid];
        z[bh * 64 + tid] = 1.0f / (s * 0.125f + 1024.0f);
    }
}

// ---------------- Y = ((SCALE*V@A + V) * z * g); v,g PRE-ACTIVATED fp32 dense ----------------
__global__ __launch_bounds__(256) void out_Y(const float* __restrict__ qkvgf,
                                             const float* __restrict__ A,
                                             const float* __restrict__ z,
                                             bf16_t* __restrict__ Y) {
    const int bh = blockIdx.x;
    const int b = bh >> 4, h = bh & 15;
    const int chunk = blockIdx.y;        // 0..15 -> 64 tokens
    const int tid = threadIdx.x;
    __shared__ float As[64][64];         // A[d][e]
    __shared__ float vs[32][64];
    __shared__ float zs[64];
    for (int i = tid; i < 4096; i += 256) As[i >> 6][i & 63] = A[(size_t)bh * 4096 + i];
    if (tid < 64) zs[tid] = z[bh * 64 + tid];
    const float* vf = qkvgf + (size_t)2 * 2048 * 1024;    // section 2
    const float* gf = qkvgf + (size_t)3 * 2048 * 1024;    // section 3
    const int e = tid & 63, trow = tid >> 6;
    const int stok = tid >> 3, se0 = (tid & 7) * 8;

    for (int t0 = chunk * 64; t0 < chunk * 64 + 64; t0 += 32) {
        __syncthreads();
        size_t rowb = (size_t)(b * 1024 + t0 + stok) * 1024 + h * 64 + se0;
        float4 v0 = *(const float4*)(&vf[rowb]);
        float4 v1 = *(const float4*)(&vf[rowb + 4]);
        *(float4*)(&vs[stok][se0]) = v0;
        *(float4*)(&vs[stok][se0 + 4]) = v1;
        __syncthreads();
#pragma unroll
        for (int kk = 0; kk < 8; ++kk) {
            int ml = trow * 8 + kk;
            int m = t0 + ml;
            float s = 0.f;
#pragma unroll 8
            for (int d = 0; d < 64; ++d) s += vs[ml][d] * As[d][e];
            float g = gf[(size_t)(b * 1024 + m) * 1024 + h * 64 + e];
            float o = (s * 0.125f + vs[ml][e]) * zs[e] * g;
            Y[((size_t)b * 1024 + h * 64 + (m >> 4)) * 1024 + ((m & 15) << 6) + e] = (bf16_t)o;
        }
    }
}

extern "C" void kernel_launch(void* const* d_in, const int* in_sizes, int n_in,
                              void* d_out, int out_size, void* d_ws, size_t ws_size,
                              hipStream_t stream) {
    const float* x      = (const float*)d_in[0];
    const float* w_qkvg = (const float*)d_in[1];
    const float* b_qkvg = (const float*)d_in[2];
    const float* w_proj = (const float*)d_in[3];
    const float* b_proj = (const float*)d_in[4];

    char* p = (char*)d_ws;
    bf16_t* xb    = (bf16_t*)p; p += (size_t)2048 * 1024 * 2;       // 4MB
    bf16_t* w1b   = (bf16_t*)p; p += (size_t)4096 * 1024 * 2;       // 8MB
    bf16_t* w2b   = (bf16_t*)p; p += (size_t)1024 * 1024 * 2;       // 2MB
    float*  qkvgf = (float*)p;  p += (size_t)4 * 2048 * 1024 * 4;   // 32MB activated fp32, 4 dense sections
    float*  Apart = (float*)p;  p += (size_t)8 * 32 * 4096 * 4;     // 4MB
    float*  Afull = (float*)p;  p += (size_t)32 * 4096 * 4;
    float*  zbuf  = (float*)p;  p += (size_t)32 * 64 * 4;
    bf16_t* Ybuf  = (bf16_t*)p; p += (size_t)2048 * 1024 * 2;       // 4MB

    // quad counts: x 524288, w_qkvg 1048576, w_proj 262144 -> 7168 blocks
    cvt3<<<7168, 256, 0, stream>>>(x, xb, 524288, w_qkvg, w1b, 1048576, w_proj, w2b, 262144);

    // merged qkvg GEMM: 128x128 tiles, 512 blocks x 512 threads (2 blocks/CU, 16 waves/CU)
    gemm_qkvg<<<512, 512, 0, stream>>>(xb, w1b, b_qkvg, qkvgf);

    attn_A<<<dim3(32, 8), 256, 0, stream>>>(qkvgf, Apart);
    reduce_A_z<<<32, 256, 0, stream>>>(Apart, Afull, zbuf);
    out_Y<<<dim3(32, 16), 256, 0, stream>>>(qkvgf, Afull, zbuf, Ybuf);
    // GEMM2: fp32 dense out (proven fast)
    gemm_bt<64, 64, 2, 2><<<512, 256, 0, stream>>>(Ybuf, w2b, b_proj, (float*)d_out, 2048, 1024);
}

// Round 16
// 94.014 us; speedup vs baseline: 1.1560x; 1.1055x over previous
//
#include <hip/hip_runtime.h>
#include <hip/hip_bf16.h>
#include <math.h>

typedef float f32x4 __attribute__((ext_vector_type(4)));
typedef __bf16 bf16_t;
typedef bf16_t bf16x8 __attribute__((ext_vector_type(8)));
typedef bf16_t bf16x4 __attribute__((ext_vector_type(4)));

__device__ __forceinline__ float act_softplus(float x) {
    return fmaxf(x, 0.f) + log1pf(expf(-fabsf(x)));
}
__device__ __forceinline__ float act_gelu(float x) {
    return 0.5f * x * (1.f + erff(x * 0.70710678118654752f));
}

// async global->LDS, 16B per lane; LDS dest = wave-uniform base + lane*16
__device__ __forceinline__ void gload_lds16(const bf16_t* g, bf16_t* l) {
    __builtin_amdgcn_global_load_lds(
        (const __attribute__((address_space(1))) unsigned int*)g,
        (__attribute__((address_space(3))) unsigned int*)l, 16, 0, 0);
}

template<int N_IMM>
__device__ __forceinline__ void wait_vmcnt() {
    if constexpr (N_IMM == 0) asm volatile("s_waitcnt vmcnt(0)" ::: "memory");
    else if constexpr (N_IMM == 2) asm volatile("s_waitcnt vmcnt(2)" ::: "memory");
    else if constexpr (N_IMM == 4) asm volatile("s_waitcnt vmcnt(4)" ::: "memory");
    else static_assert(N_IMM == 0, "unsupported vmcnt");
}

// ---------------- fused fp32 -> bf16 conversion for 3 arrays ----------------
__global__ __launch_bounds__(256) void cvt3(const float* __restrict__ a, bf16_t* __restrict__ ao, int na4,
                                            const float* __restrict__ b, bf16_t* __restrict__ bo, int nb4,
                                            const float* __restrict__ c, bf16_t* __restrict__ co, int nc4) {
    int q = blockIdx.x * 256 + threadIdx.x;   // quad index
    const float* src; bf16_t* dst;
    if (q < na4)            { src = a + (size_t)q * 4;              dst = ao + (size_t)q * 4; }
    else if (q < na4 + nb4) { int r = q - na4; src = b + (size_t)r * 4; dst = bo + (size_t)r * 4; }
    else if (q < na4 + nb4 + nc4) { int r = q - na4 - nb4; src = c + (size_t)r * 4; dst = co + (size_t)r * 4; }
    else return;
    float4 v = *reinterpret_cast<const float4*>(src);
    bf16x4 o;
    o[0] = (bf16_t)v.x; o[1] = (bf16_t)v.y; o[2] = (bf16_t)v.z; o[3] = (bf16_t)v.w;
    *reinterpret_cast<bf16x4*>(dst) = o;
}

// ---------------- merged qkvg GEMM: 4 sections in one 2048-block launch ----------------
// CHAMPION (R10, 94.5us total): static triple-buffer ring, K unrolled x3,
// counted vmcnt, raw barriers, source-preswizzled linear LDS (0 conflicts),
// bijective XCD chunk swizzle. Section = blockIdx>>9 selects weights/bias/
// output/act. Epilogue: activation at high TLP (~6 blocks/CU), then per-wave
// LDS micro-transpose so each global store instr covers 64B full cache lines.
__global__ __launch_bounds__(256) void gemm_qkvg(const bf16_t* __restrict__ A,
                                                 const bf16_t* __restrict__ Wall,
                                                 const float* __restrict__ biasAll,
                                                 bf16_t* __restrict__ OutAll) {
    constexpr int BM = 64, BN = 64, MR = 2, NR = 2;
    constexpr int K = 1024, M = 2048, N = 1024;
    constexpr int TNUM = K / 32;
    constexpr int LOADS = 2;

    __shared__ __align__(16) bf16_t Sa0[BM * 32];
    __shared__ __align__(16) bf16_t Sb0[BN * 32];
    __shared__ __align__(16) bf16_t Sa1[BM * 32];
    __shared__ __align__(16) bf16_t Sb1[BN * 32];
    __shared__ __align__(16) bf16_t Sa2[BM * 32];
    __shared__ __align__(16) bf16_t Sb2[BN * 32];

    const int sec = blockIdx.x >> 9;            // 0..3 (q,k,v,g)
    const int bid = blockIdx.x & 511;
    const bf16_t* B = Wall + (size_t)sec * 1024 * 1024;
    const float* bias = biasAll + sec * 1024;
    bf16_t* Cout = OutAll + (size_t)sec * 2048 * 1024;

    const int tid = threadIdx.x;
    const int lane = tid & 63;
    const int w = tid >> 6;
    const int wr = w >> 1, wc = w & 1;          // 2x2 waves of 32x32

    // bijective XCD swizzle within the 512-block section (512%8==0 so c==XCD)
    const int NTM = M / BM, NTN = N / BN;       // 32, 16
    const int CHM = NTM >> 3;                   // 4
    const int chunkN = (NTN * CHM) >> 3;        // 8
    const int c = bid & 7;
    const int pp = bid >> 3;
    const int mt = (c % CHM) * 8 + (pp & 7);
    const int nt = (c / CHM) * chunkN + (pp >> 3);
    const int m0 = mt * BM, n0 = nt * BN;

    const int l15 = lane & 15, lg = lane >> 4;
    const int srow = lane >> 2, pos = lane & 3;

    f32x4 acc[MR][NR] = {};

    auto stageTo2 = [&](bf16_t* Ad, bf16_t* Bd, int k0) {
        int row = w * 16 + srow;
        int ch = pos ^ ((row >> 1) & 3);
        gload_lds16(&A[(size_t)(m0 + row) * K + k0 + ch * 8], &Ad[w * 512]);
        gload_lds16(&B[(size_t)(n0 + row) * K + k0 + ch * 8], &Bd[w * 512]);
    };

    auto compute = [&](const bf16_t* Ac, const bf16_t* Bc) {
        bf16x8 af[MR], bfr[NR];
#pragma unroll
        for (int i = 0; i < MR; ++i) {
            int ar = wr * MR * 16 + i * 16 + l15;
            af[i] = *(const bf16x8*)(&Ac[ar * 32 + (lg ^ ((ar >> 1) & 3)) * 8]);
        }
#pragma unroll
        for (int j = 0; j < NR; ++j) {
            int br = wc * NR * 16 + j * 16 + l15;
            bfr[j] = *(const bf16x8*)(&Bc[br * 32 + (lg ^ ((br >> 1) & 3)) * 8]);
        }
#pragma unroll
        for (int i = 0; i < MR; ++i)
#pragma unroll
            for (int j = 0; j < NR; ++j)
                acc[i][j] = __builtin_amdgcn_mfma_f32_16x16x32_bf16(af[i], bfr[j], acc[i][j], 0, 0, 0);
    };

    stageTo2(Sa0, Sb0, 0);
    stageTo2(Sa1, Sb1, 32);

    for (int t = 0; t < TNUM - 2; t += 3) {
        wait_vmcnt<LOADS>();
        __builtin_amdgcn_s_barrier();
        __builtin_amdgcn_sched_barrier(0);
        stageTo2(Sa2, Sb2, (t + 2) * 32);
        compute(Sa0, Sb0);
        __builtin_amdgcn_sched_barrier(0);

        wait_vmcnt<LOADS>();
        __builtin_amdgcn_s_barrier();
        __builtin_amdgcn_sched_barrier(0);
        stageTo2(Sa0, Sb0, (t + 3) * 32);
        compute(Sa1, Sb1);
        __builtin_amdgcn_sched_barrier(0);

        wait_vmcnt<LOADS>();
        __builtin_amdgcn_s_barrier();
        __builtin_amdgcn_sched_barrier(0);
        stageTo2(Sa1, Sb1, (t + 4) * 32);
        compute(Sa2, Sb2);
        __builtin_amdgcn_sched_barrier(0);
    }
    wait_vmcnt<LOADS>();
    __builtin_amdgcn_s_barrier();
    __builtin_amdgcn_sched_barrier(0);
    compute(Sa0, Sb0);
    __builtin_amdgcn_sched_barrier(0);

    wait_vmcnt<0>();
    __builtin_amdgcn_s_barrier();
    __builtin_amdgcn_sched_barrier(0);
    compute(Sa1, Sb1);

    // epilogue: activation + LDS micro-transpose -> 64B-per-row bf16x8 stores.
    // Per-wave private 1KB slab in Sb2 (all waves past last barrier; slabs disjoint).
    bf16_t* slab = &Sb2[w * 512];              // 16 rows x 32 cols bf16
#pragma unroll
    for (int i = 0; i < MR; ++i) {
#pragma unroll
        for (int j = 0; j < NR; ++j) {
            int gn = n0 + wc * 32 + j * 16 + l15;
            float bv = bias[gn];
#pragma unroll
            for (int r = 0; r < 4; ++r) {
                float v = acc[i][j][r] + bv;
                float a = (sec < 2) ? act_softplus(v) : act_gelu(v);
                slab[(lg * 4 + r) * 32 + j * 16 + l15] = (bf16_t)a;
            }
        }
        // read back: 4 lanes per row, bf16x8 each -> 64B contiguous per row
        int row = lane >> 2, c8 = (lane & 3) * 8;
        bf16x8 val = *(const bf16x8*)(&slab[row * 32 + c8]);
        *(bf16x8*)(&Cout[(size_t)(m0 + wr * 32 + i * 16 + row) * N + n0 + wc * 32 + c8]) = val;
    }
}

// ---------------- GEMM2: R9 proven fp32-dense template ----------------
template<int BM, int BN, int MR, int NR>
__global__ __launch_bounds__(256) void gemm_bt(const bf16_t* __restrict__ A,
                                               const bf16_t* __restrict__ B,
                                               const float* __restrict__ bias,
                                               float* __restrict__ Cout,
                                               int M, int N) {
    constexpr int K = 1024;
    constexpr int TNUM = K / 32;
    constexpr int WCOLS = BN / (NR * 16);
    constexpr int WROWS = BM / (MR * 16);
    static_assert(WROWS * WCOLS == 4, "4 waves");
    constexpr int ASEG = BM / 64, BSEG = BN / 64;
    constexpr int LOADS = ASEG + BSEG;

    __shared__ __align__(16) bf16_t Sa0[BM * 32];
    __shared__ __align__(16) bf16_t Sb0[BN * 32];
    __shared__ __align__(16) bf16_t Sa1[BM * 32];
    __shared__ __align__(16) bf16_t Sb1[BN * 32];
    __shared__ __align__(16) bf16_t Sa2[BM * 32];
    __shared__ __align__(16) bf16_t Sb2[BN * 32];

    const int tid = threadIdx.x;
    const int lane = tid & 63;
    const int w = tid >> 6;
    const int wr = w / WCOLS, wc = w % WCOLS;

    const int NTM = M / BM, NTN = N / BN;
    const int CHM = NTM >> 3;
    const int chunkN = (NTN * CHM) >> 3;
    const int c = blockIdx.x & 7;
    const int pp = blockIdx.x >> 3;
    const int mt = (c % CHM) * 8 + (pp & 7);
    const int nt = (c / CHM) * chunkN + (pp >> 3);
    const int m0 = mt * BM, n0 = nt * BN;

    const int l15 = lane & 15, lg = lane >> 4;
    const int srow = lane >> 2, pos = lane & 3;

    f32x4 acc[MR][NR] = {};

    auto stageTo = [&](bf16_t* Ad, bf16_t* Bd, int k0) {
#pragma unroll
        for (int t = 0; t < ASEG; ++t) {
            int s = w + t * 4;
            int row = s * 16 + srow;
            int ch = pos ^ ((row >> 1) & 3);
            gload_lds16(&A[(size_t)(m0 + row) * K + k0 + ch * 8], &Ad[s * 512]);
        }
#pragma unroll
        for (int t = 0; t < BSEG; ++t) {
            int s = w + t * 4;
            int row = s * 16 + srow;
            int ch = pos ^ ((row >> 1) & 3);
            gload_lds16(&B[(size_t)(n0 + row) * K + k0 + ch * 8], &Bd[s * 512]);
        }
    };

    auto compute = [&](const bf16_t* Ac, const bf16_t* Bc) {
        bf16x8 af[MR], bfr[NR];
#pragma unroll
        for (int i = 0; i < MR; ++i) {
            int ar = wr * MR * 16 + i * 16 + l15;
            af[i] = *(const bf16x8*)(&Ac[ar * 32 + (lg ^ ((ar >> 1) & 3)) * 8]);
        }
#pragma unroll
        for (int j = 0; j < NR; ++j) {
            int br = wc * NR * 16 + j * 16 + l15;
            bfr[j] = *(const bf16x8*)(&Bc[br * 32 + (lg ^ ((br >> 1) & 3)) * 8]);
        }
#pragma unroll
        for (int i = 0; i < MR; ++i)
#pragma unroll
            for (int j = 0; j < NR; ++j)
                acc[i][j] = __builtin_amdgcn_mfma_f32_16x16x32_bf16(af[i], bfr[j], acc[i][j], 0, 0, 0);
    };

    stageTo(Sa0, Sb0, 0);
    stageTo(Sa1, Sb1, 32);

    for (int t = 0; t < TNUM - 2; t += 3) {
        wait_vmcnt<LOADS>();
        __builtin_amdgcn_s_barrier();
        __builtin_amdgcn_sched_barrier(0);
        stageTo(Sa2, Sb2, (t + 2) * 32);
        compute(Sa0, Sb0);
        __builtin_amdgcn_sched_barrier(0);

        wait_vmcnt<LOADS>();
        __builtin_amdgcn_s_barrier();
        __builtin_amdgcn_sched_barrier(0);
        stageTo(Sa0, Sb0, (t + 3) * 32);
        compute(Sa1, Sb1);
        __builtin_amdgcn_sched_barrier(0);

        wait_vmcnt<LOADS>();
        __builtin_amdgcn_s_barrier();
        __builtin_amdgcn_sched_barrier(0);
        stageTo(Sa1, Sb1, (t + 4) * 32);
        compute(Sa2, Sb2);
        __builtin_amdgcn_sched_barrier(0);
    }
    wait_vmcnt<LOADS>();
    __builtin_amdgcn_s_barrier();
    __builtin_amdgcn_sched_barrier(0);
    compute(Sa0, Sb0);
    __builtin_amdgcn_sched_barrier(0);

    wait_vmcnt<0>();
    __builtin_amdgcn_s_barrier();
    __builtin_amdgcn_sched_barrier(0);
    compute(Sa1, Sb1);

#pragma unroll
    for (int i = 0; i < MR; ++i) {
        int gm_base = m0 + wr * MR * 16 + i * 16 + lg * 4;
#pragma unroll
        for (int j = 0; j < NR; ++j) {
            int gn = n0 + wc * NR * 16 + j * 16 + l15;
            float bv = bias[gn];
#pragma unroll
            for (int r = 0; r < 4; ++r) {
                int gm = gm_base + r;
                Cout[(size_t)gm * N + gn] = acc[i][j][r] + bv;
            }
        }
    }
}

// ---------------- A = K^T Q partials per (b,h); q,k pre-activated bf16 dense ----------------
// qkvga layout: section s at s*2048*1024; element [(b*1024+tok)*1024 + h*64 + e]
__global__ __launch_bounds__(256) void attn_A(const bf16_t* __restrict__ qkvga,
                                              float* __restrict__ Apart) {
    const int bh = blockIdx.x;           // 0..31
    const int p = blockIdx.y;            // 0..7
    const int b = bh >> 4, h = bh & 15;
    const int tid = threadIdx.x;
    __shared__ float ks[32][64];
    __shared__ float qs[32][64];
    float acc[4][4] = {};
    const int dg = tid >> 4, eg = tid & 15;
    const int stok = tid >> 3, se0 = (tid & 7) * 8;
    const bf16_t* qf = qkvga;                             // section 0
    const bf16_t* kf = qkvga + (size_t)2048 * 1024;       // section 1

    for (int t0 = p * 128; t0 < p * 128 + 128; t0 += 32) {
        __syncthreads();
        size_t rowb = (size_t)(b * 1024 + t0 + stok) * 1024 + h * 64 + se0;
        bf16x8 qv8 = *(const bf16x8*)(&qf[rowb]);
        bf16x8 kv8 = *(const bf16x8*)(&kf[rowb]);
#pragma unroll
        for (int jj = 0; jj < 8; ++jj) {
            qs[stok][se0 + jj] = (float)qv8[jj];
            ks[stok][se0 + jj] = (float)kv8[jj];
        }
        __syncthreads();
#pragma unroll 8
        for (int tt = 0; tt < 32; ++tt) {
            f32x4 kv = *(const f32x4*)(&ks[tt][dg * 4]);
            f32x4 qv = *(const f32x4*)(&qs[tt][eg * 4]);
#pragma unroll
            for (int i = 0; i < 4; ++i)
#pragma unroll
                for (int j = 0; j < 4; ++j) acc[i][j] += kv[i] * qv[j];
        }
    }
    float* dst = Apart + ((size_t)p * 32 + bh) * 4096;
#pragma unroll
    for (int i = 0; i < 4; ++i)
#pragma unroll
        for (int j = 0; j < 4; ++j)
            dst[(dg * 4 + i) * 64 + eg * 4 + j] = acc[i][j];
}

// ---------------- reduce partials -> A, compute z ----------------
__global__ __launch_bounds__(256) void reduce_A_z(const float* __restrict__ Apart,
                                                  float* __restrict__ A,
                                                  float* __restrict__ z) {
    const int bh = blockIdx.x;
    const int tid = threadIdx.x;
    __shared__ float As[4096];
    for (int i0 = tid * 4; i0 < 4096; i0 += 1024) {
        f32x4 s = {};
#pragma unroll
        for (int p = 0; p < 8; ++p) {
            f32x4 v = *(const f32x4*)(&Apart[((size_t)p * 32 + bh) * 4096 + i0]);
            s += v;
        }
        *(f32x4*)(&As[i0]) = s;
        *(f32x4*)(&A[(size_t)bh * 4096 + i0]) = s;
    }
    __syncthreads();
    if (tid < 64) {
        float s = 0.f;
#pragma unroll 8
        for (int d = 0; d < 64; ++d) s += As[d * 64 + tid];
        z[bh * 64 + tid] = 1.0f / (s * 0.125f + 1024.0f);
    }
}

// ---------------- Y = ((SCALE*V@A + V) * z * g); v,g pre-activated bf16 dense ----------------
__global__ __launch_bounds__(256) void out_Y(const bf16_t* __restrict__ qkvga,
                                             const float* __restrict__ A,
                                             const float* __restrict__ z,
                                             bf16_t* __restrict__ Y) {
    const int bh = blockIdx.x;
    const int b = bh >> 4, h = bh & 15;
    const int chunk = blockIdx.y;        // 0..15 -> 64 tokens
    const int tid = threadIdx.x;
    __shared__ float As[64][64];         // A[d][e]
    __shared__ float vs[32][64];
    __shared__ float zs[64];
    for (int i = tid; i < 4096; i += 256) As[i >> 6][i & 63] = A[(size_t)bh * 4096 + i];
    if (tid < 64) zs[tid] = z[bh * 64 + tid];
    const bf16_t* vf = qkvga + (size_t)2 * 2048 * 1024;   // section 2
    const bf16_t* gf = qkvga + (size_t)3 * 2048 * 1024;   // section 3
    const int e = tid & 63, trow = tid >> 6;
    const int stok = tid >> 3, se0 = (tid & 7) * 8;

    for (int t0 = chunk * 64; t0 < chunk * 64 + 64; t0 += 32) {
        __syncthreads();
        bf16x8 vv8 = *(const bf16x8*)(&vf[(size_t)(b * 1024 + t0 + stok) * 1024 + h * 64 + se0]);
#pragma unroll
        for (int jj = 0; jj < 8; ++jj) vs[stok][se0 + jj] = (float)vv8[jj];
        __syncthreads();
#pragma unroll
        for (int kk = 0; kk < 8; ++kk) {
            int ml = trow * 8 + kk;
            int m = t0 + ml;
            float s = 0.f;
#pragma unroll 8
            for (int d = 0; d < 64; ++d) s += vs[ml][d] * As[d][e];
            float g = (float)gf[(size_t)(b * 1024 + m) * 1024 + h * 64 + e];
            float o = (s * 0.125f + vs[ml][e]) * zs[e] * g;
            Y[((size_t)b * 1024 + h * 64 + (m >> 4)) * 1024 + ((m & 15) << 6) + e] = (bf16_t)o;
        }
    }
}

extern "C" void kernel_launch(void* const* d_in, const int* in_sizes, int n_in,
                              void* d_out, int out_size, void* d_ws, size_t ws_size,
                              hipStream_t stream) {
    const float* x      = (const float*)d_in[0];
    const float* w_qkvg = (const float*)d_in[1];
    const float* b_qkvg = (const float*)d_in[2];
    const float* w_proj = (const float*)d_in[3];
    const float* b_proj = (const float*)d_in[4];

    char* p = (char*)d_ws;
    bf16_t* xb    = (bf16_t*)p; p += (size_t)2048 * 1024 * 2;     // 4MB
    bf16_t* w1b   = (bf16_t*)p; p += (size_t)4096 * 1024 * 2;     // 8MB
    bf16_t* w2b   = (bf16_t*)p; p += (size_t)1024 * 1024 * 2;     // 2MB
    bf16_t* qkvga = (bf16_t*)p; p += (size_t)4 * 2048 * 1024 * 2; // 16MB activated bf16, 4 dense sections
    float*  Apart = (float*)p;  p += (size_t)8 * 32 * 4096 * 4;   // 4MB
    float*  Afull = (float*)p;  p += (size_t)32 * 4096 * 4;
    float*  zbuf  = (float*)p;  p += (size_t)32 * 64 * 4;
    bf16_t* Ybuf  = (bf16_t*)p; p += (size_t)2048 * 1024 * 2;     // 4MB

    // quad counts: x 524288, w_qkvg 1048576, w_proj 262144 -> 7168 blocks
    cvt3<<<7168, 256, 0, stream>>>(x, xb, 524288, w_qkvg, w1b, 1048576, w_proj, w2b, 262144);

    // merged qkvg GEMM: 4 sections x 512 blocks = 2048 blocks (~6/CU resident)
    gemm_qkvg<<<2048, 256, 0, stream>>>(xb, w1b, b_qkvg, qkvga);

    attn_A<<<dim3(32, 8), 256, 0, stream>>>(qkvga, Apart);
    reduce_A_z<<<32, 256, 0, stream>>>(Apart, Afull, zbuf);
    out_Y<<<dim3(32, 16), 256, 0, stream>>>(qkvga, Afull, zbuf, Ybuf);
    // GEMM2: fp32 dense out (proven fast)
    gemm_bt<64, 64, 2, 2><<<512, 256, 0, stream>>>(Ybuf, w2b, b_proj, (float*)d_out, 2048, 1024);
}

// Round 17
// 93.960 us; speedup vs baseline: 1.1567x; 1.0006x over previous
//
#include <hip/hip_runtime.h>
#include <hip/hip_bf16.h>
#include <math.h>

typedef float f32x4 __attribute__((ext_vector_type(4)));
typedef __bf16 bf16_t;
typedef bf16_t bf16x8 __attribute__((ext_vector_type(8)));
typedef bf16_t bf16x4 __attribute__((ext_vector_type(4)));

__device__ __forceinline__ float act_softplus(float x) {
    return fmaxf(x, 0.f) + log1pf(expf(-fabsf(x)));
}
__device__ __forceinline__ float act_gelu(float x) {
    return 0.5f * x * (1.f + erff(x * 0.70710678118654752f));
}

// async global->LDS, 16B per lane; LDS dest = wave-uniform base + lane*16
__device__ __forceinline__ void gload_lds16(const bf16_t* g, bf16_t* l) {
    __builtin_amdgcn_global_load_lds(
        (const __attribute__((address_space(1))) unsigned int*)g,
        (__attribute__((address_space(3))) unsigned int*)l, 16, 0, 0);
}

template<int N_IMM>
__device__ __forceinline__ void wait_vmcnt() {
    if constexpr (N_IMM == 0) asm volatile("s_waitcnt vmcnt(0)" ::: "memory");
    else if constexpr (N_IMM == 2) asm volatile("s_waitcnt vmcnt(2)" ::: "memory");
    else if constexpr (N_IMM == 4) asm volatile("s_waitcnt vmcnt(4)" ::: "memory");
    else static_assert(N_IMM == 0, "unsupported vmcnt");
}

// ---------------- fused fp32 -> bf16 conversion for 3 arrays ----------------
__global__ __launch_bounds__(256) void cvt3(const float* __restrict__ a, bf16_t* __restrict__ ao, int na4,
                                            const float* __restrict__ b, bf16_t* __restrict__ bo, int nb4,
                                            const float* __restrict__ c, bf16_t* __restrict__ co, int nc4) {
    int q = blockIdx.x * 256 + threadIdx.x;   // quad index
    const float* src; bf16_t* dst;
    if (q < na4)            { src = a + (size_t)q * 4;              dst = ao + (size_t)q * 4; }
    else if (q < na4 + nb4) { int r = q - na4; src = b + (size_t)r * 4; dst = bo + (size_t)r * 4; }
    else if (q < na4 + nb4 + nc4) { int r = q - na4 - nb4; src = c + (size_t)r * 4; dst = co + (size_t)r * 4; }
    else return;
    float4 v = *reinterpret_cast<const float4*>(src);
    bf16x4 o;
    o[0] = (bf16_t)v.x; o[1] = (bf16_t)v.y; o[2] = (bf16_t)v.z; o[3] = (bf16_t)v.w;
    *reinterpret_cast<bf16x4*>(dst) = o;
}

// ---------------- merged qkvg GEMM: champion structure, BK=64 (16 fat K-steps) ----------------
// R17: single variable vs R16 champion -- BK 32->64. 16 steps x {4 loads/thread,
// counted vmcnt(4), 2 raw barriers, 8 MFMA/wave}. Tests fixed-per-step-latency
// vs staging-BW model. LDS 32KB (2 bufs x 8KB x 2 ops) -> 5 blocks/CU.
// Source-preswizzled linear LDS for 128B rows: ch = slot ^ (row&7); read side
// chunk^(ar&7) -> 2-way max conflicts. Section/XCD mapping, slab epilogue
// (64B-line activated bf16) identical to champion.
__global__ __launch_bounds__(256) void gemm_qkvg(const bf16_t* __restrict__ A,
                                                 const bf16_t* __restrict__ Wall,
                                                 const float* __restrict__ biasAll,
                                                 bf16_t* __restrict__ OutAll) {
    constexpr int BM = 64, BN = 64, MR = 2, NR = 2;
    constexpr int K = 1024, M = 2048, N = 1024;
    constexpr int TNUM = K / 64;                // 16, even
    constexpr int LOADS = 4;

    __shared__ __align__(16) bf16_t Sa0[BM * 64];   // 8KB each
    __shared__ __align__(16) bf16_t Sb0[BN * 64];
    __shared__ __align__(16) bf16_t Sa1[BM * 64];
    __shared__ __align__(16) bf16_t Sb1[BN * 64];

    const int sec = blockIdx.x >> 9;            // 0..3 (q,k,v,g)
    const int bid = blockIdx.x & 511;
    const bf16_t* B = Wall + (size_t)sec * 1024 * 1024;
    const float* bias = biasAll + sec * 1024;
    bf16_t* Cout = OutAll + (size_t)sec * 2048 * 1024;

    const int tid = threadIdx.x;
    const int lane = tid & 63;
    const int w = tid >> 6;
    const int wr = w >> 1, wc = w & 1;          // 2x2 waves of 32x32

    // bijective XCD swizzle within the 512-block section (512%8==0 so c==XCD)
    const int NTM = M / BM, NTN = N / BN;       // 32, 16
    const int CHM = NTM >> 3;                   // 4
    const int chunkN = (NTN * CHM) >> 3;        // 8
    const int c = bid & 7;
    const int pp = bid >> 3;
    const int mt = (c % CHM) * 8 + (pp & 7);
    const int nt = (c / CHM) * chunkN + (pp >> 3);
    const int m0 = mt * BM, n0 = nt * BN;

    const int l15 = lane & 15, lg = lane >> 4;
    const int srow8 = lane >> 3;                // 0..7 rows per wave-call
    const int slot = lane & 7;                  // 16B slot within 128B row

    f32x4 acc[MR][NR] = {};

    // stage one full 64x64 bf16 tile per operand: 2 calls x (64 lanes x 16B = 8 rows)
    auto stageTo = [&](bf16_t* Ad, bf16_t* Bd, int k0) {
#pragma unroll
        for (int t = 0; t < 2; ++t) {
            int row = t * 32 + w * 8 + srow8;   // 0..63
            int ch = slot ^ (row & 7);
            gload_lds16(&A[(size_t)(m0 + row) * K + k0 + ch * 8], &Ad[(t * 32 + w * 8) * 64]);
            gload_lds16(&B[(size_t)(n0 + row) * K + k0 + ch * 8], &Bd[(t * 32 + w * 8) * 64]);
        }
    };

    auto compute = [&](const bf16_t* Ac, const bf16_t* Bc) {
#pragma unroll
        for (int kk = 0; kk < 2; ++kk) {        // two K=32 halves of the 64-wide tile
            bf16x8 af[MR], bfr[NR];
#pragma unroll
            for (int i = 0; i < MR; ++i) {
                int ar = wr * 32 + i * 16 + l15;
                af[i] = *(const bf16x8*)(&Ac[ar * 64 + ((kk * 4 + lg) ^ (ar & 7)) * 8]);
            }
#pragma unroll
            for (int j = 0; j < NR; ++j) {
                int br = wc * 32 + j * 16 + l15;
                bfr[j] = *(const bf16x8*)(&Bc[br * 64 + ((kk * 4 + lg) ^ (br & 7)) * 8]);
            }
#pragma unroll
            for (int i = 0; i < MR; ++i)
#pragma unroll
                for (int j = 0; j < NR; ++j)
                    acc[i][j] = __builtin_amdgcn_mfma_f32_16x16x32_bf16(af[i], bfr[j], acc[i][j], 0, 0, 0);
        }
    };

    stageTo(Sa0, Sb0, 0);
    for (int t = 0; t < TNUM; t += 2) {
        // phase A: tile t in S0
        if (t + 1 < TNUM) { stageTo(Sa1, Sb1, (t + 1) * 64); wait_vmcnt<LOADS>(); }
        else              { wait_vmcnt<0>(); }
        __builtin_amdgcn_s_barrier();
        __builtin_amdgcn_sched_barrier(0);
        compute(Sa0, Sb0);
        __builtin_amdgcn_sched_barrier(0);
        __builtin_amdgcn_s_barrier();

        // phase B: tile t+1 in S1
        if (t + 2 < TNUM) { stageTo(Sa0, Sb0, (t + 2) * 64); wait_vmcnt<LOADS>(); }
        else              { wait_vmcnt<0>(); }
        __builtin_amdgcn_s_barrier();
        __builtin_amdgcn_sched_barrier(0);
        compute(Sa1, Sb1);
        __builtin_amdgcn_sched_barrier(0);
        __builtin_amdgcn_s_barrier();
    }

    // epilogue: activation + LDS micro-transpose -> 64B-per-row bf16x8 stores.
    // Per-wave private 1KB slab in Sb0 (all reads of Sb0 completed before the
    // final barrier; slabs disjoint per wave).
    bf16_t* slab = &Sb0[w * 512];              // 16 rows x 32 cols bf16
#pragma unroll
    for (int i = 0; i < MR; ++i) {
#pragma unroll
        for (int j = 0; j < NR; ++j) {
            int gn = n0 + wc * 32 + j * 16 + l15;
            float bv = bias[gn];
#pragma unroll
            for (int r = 0; r < 4; ++r) {
                float v = acc[i][j][r] + bv;
                float a = (sec < 2) ? act_softplus(v) : act_gelu(v);
                slab[(lg * 4 + r) * 32 + j * 16 + l15] = (bf16_t)a;
            }
        }
        // read back: 4 lanes per row, bf16x8 each -> 64B contiguous per row
        int row = lane >> 2, c8 = (lane & 3) * 8;
        bf16x8 val = *(const bf16x8*)(&slab[row * 32 + c8]);
        *(bf16x8*)(&Cout[(size_t)(m0 + wr * 32 + i * 16 + row) * N + n0 + wc * 32 + c8]) = val;
    }
}

// ---------------- GEMM2: R9 proven fp32-dense template (unchanged) ----------------
template<int BM, int BN, int MR, int NR>
__global__ __launch_bounds__(256) void gemm_bt(const bf16_t* __restrict__ A,
                                               const bf16_t* __restrict__ B,
                                               const float* __restrict__ bias,
                                               float* __restrict__ Cout,
                                               int M, int N) {
    constexpr int K = 1024;
    constexpr int TNUM = K / 32;
    constexpr int WCOLS = BN / (NR * 16);
    constexpr int WROWS = BM / (MR * 16);
    static_assert(WROWS * WCOLS == 4, "4 waves");
    constexpr int ASEG = BM / 64, BSEG = BN / 64;
    constexpr int LOADS = ASEG + BSEG;

    __shared__ __align__(16) bf16_t Sa0[BM * 32];
    __shared__ __align__(16) bf16_t Sb0[BN * 32];
    __shared__ __align__(16) bf16_t Sa1[BM * 32];
    __shared__ __align__(16) bf16_t Sb1[BN * 32];
    __shared__ __align__(16) bf16_t Sa2[BM * 32];
    __shared__ __align__(16) bf16_t Sb2[BN * 32];

    const int tid = threadIdx.x;
    const int lane = tid & 63;
    const int w = tid >> 6;
    const int wr = w / WCOLS, wc = w % WCOLS;

    const int NTM = M / BM, NTN = N / BN;
    const int CHM = NTM >> 3;
    const int chunkN = (NTN * CHM) >> 3;
    const int c = blockIdx.x & 7;
    const int pp = blockIdx.x >> 3;
    const int mt = (c % CHM) * 8 + (pp & 7);
    const int nt = (c / CHM) * chunkN + (pp >> 3);
    const int m0 = mt * BM, n0 = nt * BN;

    const int l15 = lane & 15, lg = lane >> 4;
    const int srow = lane >> 2, pos = lane & 3;

    f32x4 acc[MR][NR] = {};

    auto stageTo = [&](bf16_t* Ad, bf16_t* Bd, int k0) {
#pragma unroll
        for (int t = 0; t < ASEG; ++t) {
            int s = w + t * 4;
            int row = s * 16 + srow;
            int ch = pos ^ ((row >> 1) & 3);
            gload_lds16(&A[(size_t)(m0 + row) * K + k0 + ch * 8], &Ad[s * 512]);
        }
#pragma unroll
        for (int t = 0; t < BSEG; ++t) {
            int s = w + t * 4;
            int row = s * 16 + srow;
            int ch = pos ^ ((row >> 1) & 3);
            gload_lds16(&B[(size_t)(n0 + row) * K + k0 + ch * 8], &Bd[s * 512]);
        }
    };

    auto compute = [&](const bf16_t* Ac, const bf16_t* Bc) {
        bf16x8 af[MR], bfr[NR];
#pragma unroll
        for (int i = 0; i < MR; ++i) {
            int ar = wr * MR * 16 + i * 16 + l15;
            af[i] = *(const bf16x8*)(&Ac[ar * 32 + (lg ^ ((ar >> 1) & 3)) * 8]);
        }
#pragma unroll
        for (int j = 0; j < NR; ++j) {
            int br = wc * NR * 16 + j * 16 + l15;
            bfr[j] = *(const bf16x8*)(&Bc[br * 32 + (lg ^ ((br >> 1) & 3)) * 8]);
        }
#pragma unroll
        for (int i = 0; i < MR; ++i)
#pragma unroll
            for (int j = 0; j < NR; ++j)
                acc[i][j] = __builtin_amdgcn_mfma_f32_16x16x32_bf16(af[i], bfr[j], acc[i][j], 0, 0, 0);
    };

    stageTo(Sa0, Sb0, 0);
    stageTo(Sa1, Sb1, 32);

    for (int t = 0; t < TNUM - 2; t += 3) {
        wait_vmcnt<LOADS>();
        __builtin_amdgcn_s_barrier();
        __builtin_amdgcn_sched_barrier(0);
        stageTo(Sa2, Sb2, (t + 2) * 32);
        compute(Sa0, Sb0);
        __builtin_amdgcn_sched_barrier(0);

        wait_vmcnt<LOADS>();
        __builtin_amdgcn_s_barrier();
        __builtin_amdgcn_sched_barrier(0);
        stageTo(Sa0, Sb0, (t + 3) * 32);
        compute(Sa1, Sb1);
        __builtin_amdgcn_sched_barrier(0);

        wait_vmcnt<LOADS>();
        __builtin_amdgcn_s_barrier();
        __builtin_amdgcn_sched_barrier(0);
        stageTo(Sa1, Sb1, (t + 4) * 32);
        compute(Sa2, Sb2);
        __builtin_amdgcn_sched_barrier(0);
    }
    wait_vmcnt<LOADS>();
    __builtin_amdgcn_s_barrier();
    __builtin_amdgcn_sched_barrier(0);
    compute(Sa0, Sb0);
    __builtin_amdgcn_sched_barrier(0);

    wait_vmcnt<0>();
    __builtin_amdgcn_s_barrier();
    __builtin_amdgcn_sched_barrier(0);
    compute(Sa1, Sb1);

#pragma unroll
    for (int i = 0; i < MR; ++i) {
        int gm_base = m0 + wr * MR * 16 + i * 16 + lg * 4;
#pragma unroll
        for (int j = 0; j < NR; ++j) {
            int gn = n0 + wc * NR * 16 + j * 16 + l15;
            float bv = bias[gn];
#pragma unroll
            for (int r = 0; r < 4; ++r) {
                int gm = gm_base + r;
                Cout[(size_t)gm * N + gn] = acc[i][j][r] + bv;
            }
        }
    }
}

// ---------------- A = K^T Q partials per (b,h); q,k pre-activated bf16 dense ----------------
// qkvga layout: section s at s*2048*1024; element [(b*1024+tok)*1024 + h*64 + e]
__global__ __launch_bounds__(256) void attn_A(const bf16_t* __restrict__ qkvga,
                                              float* __restrict__ Apart) {
    const int bh = blockIdx.x;           // 0..31
    const int p = blockIdx.y;            // 0..7
    const int b = bh >> 4, h = bh & 15;
    const int tid = threadIdx.x;
    __shared__ float ks[32][64];
    __shared__ float qs[32][64];
    float acc[4][4] = {};
    const int dg = tid >> 4, eg = tid & 15;
    const int stok = tid >> 3, se0 = (tid & 7) * 8;
    const bf16_t* qf = qkvga;                             // section 0
    const bf16_t* kf = qkvga + (size_t)2048 * 1024;       // section 1

    for (int t0 = p * 128; t0 < p * 128 + 128; t0 += 32) {
        __syncthreads();
        size_t rowb = (size_t)(b * 1024 + t0 + stok) * 1024 + h * 64 + se0;
        bf16x8 qv8 = *(const bf16x8*)(&qf[rowb]);
        bf16x8 kv8 = *(const bf16x8*)(&kf[rowb]);
#pragma unroll
        for (int jj = 0; jj < 8; ++jj) {
            qs[stok][se0 + jj] = (float)qv8[jj];
            ks[stok][se0 + jj] = (float)kv8[jj];
        }
        __syncthreads();
#pragma unroll 8
        for (int tt = 0; tt < 32; ++tt) {
            f32x4 kv = *(const f32x4*)(&ks[tt][dg * 4]);
            f32x4 qv = *(const f32x4*)(&qs[tt][eg * 4]);
#pragma unroll
            for (int i = 0; i < 4; ++i)
#pragma unroll
                for (int j = 0; j < 4; ++j) acc[i][j] += kv[i] * qv[j];
        }
    }
    float* dst = Apart + ((size_t)p * 32 + bh) * 4096;
#pragma unroll
    for (int i = 0; i < 4; ++i)
#pragma unroll
        for (int j = 0; j < 4; ++j)
            dst[(dg * 4 + i) * 64 + eg * 4 + j] = acc[i][j];
}

// ---------------- reduce partials -> A, compute z ----------------
__global__ __launch_bounds__(256) void reduce_A_z(const float* __restrict__ Apart,
                                                  float* __restrict__ A,
                                                  float* __restrict__ z) {
    const int bh = blockIdx.x;
    const int tid = threadIdx.x;
    __shared__ float As[4096];
    for (int i0 = tid * 4; i0 < 4096; i0 += 1024) {
        f32x4 s = {};
#pragma unroll
        for (int p = 0; p < 8; ++p) {
            f32x4 v = *(const f32x4*)(&Apart[((size_t)p * 32 + bh) * 4096 + i0]);
            s += v;
        }
        *(f32x4*)(&As[i0]) = s;
        *(f32x4*)(&A[(size_t)bh * 4096 + i0]) = s;
    }
    __syncthreads();
    if (tid < 64) {
        float s = 0.f;
#pragma unroll 8
        for (int d = 0; d < 64; ++d) s += As[d * 64 + tid];
        z[bh * 64 + tid] = 1.0f / (s * 0.125f + 1024.0f);
    }
}

// ---------------- Y = ((SCALE*V@A + V) * z * g); v,g pre-activated bf16 dense ----------------
__global__ __launch_bounds__(256) void out_Y(const bf16_t* __restrict__ qkvga,
                                             const float* __restrict__ A,
                                             const float* __restrict__ z,
                                             bf16_t* __restrict__ Y) {
    const int bh = blockIdx.x;
    const int b = bh >> 4, h = bh & 15;
    const int chunk = blockIdx.y;        // 0..15 -> 64 tokens
    const int tid = threadIdx.x;
    __shared__ float As[64][64];         // A[d][e]
    __shared__ float vs[32][64];
    __shared__ float zs[64];
    for (int i = tid; i < 4096; i += 256) As[i >> 6][i & 63] = A[(size_t)bh * 4096 + i];
    if (tid < 64) zs[tid] = z[bh * 64 + tid];
    const bf16_t* vf = qkvga + (size_t)2 * 2048 * 1024;   // section 2
    const bf16_t* gf = qkvga + (size_t)3 * 2048 * 1024;   // section 3
    const int e = tid & 63, trow = tid >> 6;
    const int stok = tid >> 3, se0 = (tid & 7) * 8;

    for (int t0 = chunk * 64; t0 < chunk * 64 + 64; t0 += 32) {
        __syncthreads();
        bf16x8 vv8 = *(const bf16x8*)(&vf[(size_t)(b * 1024 + t0 + stok) * 1024 + h * 64 + se0]);
#pragma unroll
        for (int jj = 0; jj < 8; ++jj) vs[stok][se0 + jj] = (float)vv8[jj];
        __syncthreads();
#pragma unroll
        for (int kk = 0; kk < 8; ++kk) {
            int ml = trow * 8 + kk;
            int m = t0 + ml;
            float s = 0.f;
#pragma unroll 8
            for (int d = 0; d < 64; ++d) s += vs[ml][d] * As[d][e];
            float g = (float)gf[(size_t)(b * 1024 + m) * 1024 + h * 64 + e];
            float o = (s * 0.125f + vs[ml][e]) * zs[e] * g;
            Y[((size_t)b * 1024 + h * 64 + (m >> 4)) * 1024 + ((m & 15) << 6) + e] = (bf16_t)o;
        }
    }
}

extern "C" void kernel_launch(void* const* d_in, const int* in_sizes, int n_in,
                              void* d_out, int out_size, void* d_ws, size_t ws_size,
                              hipStream_t stream) {
    const float* x      = (const float*)d_in[0];
    const float* w_qkvg = (const float*)d_in[1];
    const float* b_qkvg = (const float*)d_in[2];
    const float* w_proj = (const float*)d_in[3];
    const float* b_proj = (const float*)d_in[4];

    char* p = (char*)d_ws;
    bf16_t* xb    = (bf16_t*)p; p += (size_t)2048 * 1024 * 2;     // 4MB
    bf16_t* w1b   = (bf16_t*)p; p += (size_t)4096 * 1024 * 2;     // 8MB
    bf16_t* w2b   = (bf16_t*)p; p += (size_t)1024 * 1024 * 2;     // 2MB
    bf16_t* qkvga = (bf16_t*)p; p += (size_t)4 * 2048 * 1024 * 2; // 16MB activated bf16, 4 dense sections
    float*  Apart = (float*)p;  p += (size_t)8 * 32 * 4096 * 4;   // 4MB
    float*  Afull = (float*)p;  p += (size_t)32 * 4096 * 4;
    float*  zbuf  = (float*)p;  p += (size_t)32 * 64 * 4;
    bf16_t* Ybuf  = (bf16_t*)p; p += (size_t)2048 * 1024 * 2;     // 4MB

    // quad counts: x 524288, w_qkvg 1048576, w_proj 262144 -> 7168 blocks
    cvt3<<<7168, 256, 0, stream>>>(x, xb, 524288, w_qkvg, w1b, 1048576, w_proj, w2b, 262144);

    // merged qkvg GEMM: 4 sections x 512 blocks = 2048 blocks, BK=64 (16 fat K-steps)
    gemm_qkvg<<<2048, 256, 0, stream>>>(xb, w1b, b_qkvg, qkvga);

    attn_A<<<dim3(32, 8), 256, 0, stream>>>(qkvga, Apart);
    reduce_A_z<<<32, 256, 0, stream>>>(Apart, Afull, zbuf);
    out_Y<<<dim3(32, 16), 256, 0, stream>>>(qkvga, Afull, zbuf, Ybuf);
    // GEMM2: fp32 dense out (proven fast)
    gemm_bt<64, 64, 2, 2><<<512, 256, 0, stream>>>(Ybuf, w2b, b_proj, (float*)d_out, 2048, 1024);
}